// Round 5
// baseline (89.410 us; speedup 1.0000x reference)
//
#include <hip/hip_runtime.h>

// BinaryLinear three-kernel:
//   cvt_x : X f32 -> bf16 (RNE)
//   bin_w : W f32 (KxN) -> binarized bf16 {0,1}, transposed to NxK
//   gemm_32 : 256x256 tile, BK=64, 8 waves, dbuf 128KB LDS, 4-phase
//             counted-vmcnt pipeline (hardened chain), XOR swizzle,
//             mfma_f32_32x32x16_bf16 (2495 TF ceiling vs 2075 for 16x16).
// Fallback: round-1 fused kernel if ws too small.

#define MDIM 8192
#define NDIM 2048
#define KDIM 2048
#define NT   (KDIM / 64)          // 32 K-tiles

typedef __attribute__((ext_vector_type(8))) short short8;
typedef __attribute__((ext_vector_type(4))) float float4v;
typedef __attribute__((ext_vector_type(4))) float f32x4;
typedef __attribute__((ext_vector_type(16))) float f32x16;
typedef __attribute__((ext_vector_type(4))) unsigned short ushort4v;
typedef __attribute__((ext_vector_type(8))) unsigned short ushort8v;

__device__ __forceinline__ unsigned short f2bf(float f) {
    union { float f; unsigned u; } v; v.f = f;
    unsigned r = v.u + 0x7FFFu + ((v.u >> 16) & 1u);
    return (unsigned short)(r >> 16);
}

__device__ __forceinline__ void gload_lds16(void* l, const void* g) {
    __builtin_amdgcn_global_load_lds(
        (const __attribute__((address_space(1))) unsigned int*)g,
        (__attribute__((address_space(3))) unsigned int*)l,
        16, 0, 0);
}

#define FENCE asm volatile("" ::: "memory")
#define BAR do { FENCE; __builtin_amdgcn_s_barrier(); FENCE; } while (0)

// ---------------- pass 1a: X -> bf16 ----------------
__global__ __launch_bounds__(256) void cvt_x(const float* __restrict__ X,
                                             unsigned short* __restrict__ Xb) {
    size_t i = ((size_t)blockIdx.x * 256 + threadIdx.x) * 8;
    float4v a = *reinterpret_cast<const float4v*>(X + i);
    float4v b = *reinterpret_cast<const float4v*>(X + i + 4);
    ushort8v o;
    o[0] = f2bf(a[0]); o[1] = f2bf(a[1]); o[2] = f2bf(a[2]); o[3] = f2bf(a[3]);
    o[4] = f2bf(b[0]); o[5] = f2bf(b[1]); o[6] = f2bf(b[2]); o[7] = f2bf(b[3]);
    *reinterpret_cast<ushort8v*>(Xb + i) = o;
}

// ---------------- pass 1b: binarize + transpose W ----------------
__global__ __launch_bounds__(256) void bin_w(const float* __restrict__ W,
                                             unsigned short* __restrict__ Wt) {
    __shared__ __align__(16) unsigned short T[64][72];
    const int t = threadIdx.x;
    const int k0 = (blockIdx.x >> 5) * 64;
    const int n0 = (blockIdx.x & 31) * 64;
    const int kr = t >> 4;
    const int nc = (t & 15) * 4;
#pragma unroll
    for (int rr = 0; rr < 4; ++rr) {
        int k = k0 + rr * 16 + kr;
        float4v w4 = *reinterpret_cast<const float4v*>(W + (size_t)k * NDIM + n0 + nc);
#pragma unroll
        for (int c = 0; c < 4; ++c)
            T[nc + c][rr * 16 + kr] = (w4[c] > 0.0f) ? (unsigned short)0x3F80u
                                                     : (unsigned short)0u;
    }
    __syncthreads();
    const int nl = t >> 2, ch = t & 3;
    ushort8v v0 = *reinterpret_cast<const ushort8v*>(&T[nl][ch * 16]);
    ushort8v v1 = *reinterpret_cast<const ushort8v*>(&T[nl][ch * 16 + 8]);
    unsigned short* dst = Wt + (size_t)(n0 + nl) * KDIM + k0 + ch * 16;
    *reinterpret_cast<ushort8v*>(dst) = v0;
    *reinterpret_cast<ushort8v*>(dst + 8) = v1;
}

// ---------------- pass 2: 256x256 GEMM, 32x32x16 MFMA ----------------
// LDS per buffer (64 KB): A [256 rows][64 k] at +0, B at +32768; row = 128 B;
// slot s of row r holds global slot s^(r&7) (swizzle via pre-swizzled source).
// Chunk c (8 KB) = 64 rows. Wave tile 128x64: mi 0..3 (32-row), ni 0..1.
// Phase (h,kh): mi-pair {2h,2h+1}, ks-pair {2kh,2kh+1}; order
// (0,0),(1,0),(0,1),(1,1). Chunk deps: h=0 -> A chunk 2wr, h=1 -> 2wr+1.
// Stages for t+1: ph0 B0,B2 | ph1 B1,B3 | ph2 A0,A2 | ph3 A1,A3.
// Waits: ph0 vmcnt(2) [drains B*,A0,A2 of t]; ph1 vmcnt(2) [drains A1,A3
// of t; vmcnt(0) on last tile].
__global__ __launch_bounds__(512, 1) void gemm_32(const unsigned short* __restrict__ A,
                                                  const unsigned short* __restrict__ Bt,
                                                  float* __restrict__ O) {
    extern __shared__ char lds[];
    const int tid  = threadIdx.x;
    const int lane = tid & 63;
    const int w    = tid >> 6;       // 0..7
    const int wr   = w >> 2;         // 0..1
    const int wc   = w & 3;          // 0..3

    int id  = blockIdx.x;            // 256 blocks, %8==0 -> bijective
    int swz = (id & 7) * 32 + (id >> 3);
    const int bm = swz >> 3;         // 0..31
    const int bn = swz & 7;          // 0..7

    // staging source: row = w*8 + l3, pre-swizzled slot (l7 ^ l3)
    const int l3 = lane >> 3, l7 = lane & 7;
    const int srcOff = (w * 8 + l3) * (KDIM * 2) + ((l7 ^ l3) << 4);
    const char* gA = (const char*)A + (size_t)(bm * 256) * (KDIM * 2) + srcOff;
    const char* gB = (const char*)Bt + (size_t)(bn * 256) * (KDIM * 2) + srcOff;

    // fragment read constants (32x32x16: row = lane&31, k-octet = lane>>5)
    const int fr = lane & 31;        // row within 32-block
    const int fg = lane >> 5;        // k-octet select
    int sl[4];                       // swizzled slot byte offset per ks
#pragma unroll
    for (int ks = 0; ks < 4; ++ks)
        sl[ks] = ((((ks << 1) | fg)) ^ (fr & 7)) << 4;
    const int aRowB = (wr * 128 + fr) * 128;          // + mi*4096 + sl[ks]
    const int bRowB = 32768 + (wc * 64 + fr) * 128;   // + ni*4096 + sl[ks]

    f32x16 acc[4][2];
#pragma unroll
    for (int i = 0; i < 4; ++i)
#pragma unroll
        for (int j = 0; j < 2; ++j)
#pragma unroll
            for (int r = 0; r < 16; ++r) acc[i][j][r] = 0.f;

    // prologue: stage tile 0, drain, barrier
    gload_lds16(lds + 32768 + 0 * 8192 + w * 1024, gB + 0 * 262144);
    gload_lds16(lds + 32768 + 2 * 8192 + w * 1024, gB + 2 * 262144);
    gload_lds16(lds + 32768 + 1 * 8192 + w * 1024, gB + 1 * 262144);
    gload_lds16(lds + 32768 + 3 * 8192 + w * 1024, gB + 3 * 262144);
    gload_lds16(lds + 0 * 8192 + w * 1024, gA + 0 * 262144);
    gload_lds16(lds + 2 * 8192 + w * 1024, gA + 2 * 262144);
    gload_lds16(lds + 1 * 8192 + w * 1024, gA + 1 * 262144);
    gload_lds16(lds + 3 * 8192 + w * 1024, gA + 3 * 262144);
    asm volatile("s_waitcnt vmcnt(0)" ::: "memory");
    BAR;

    short8 af[2][2], bfr[2][2];

    for (int t = 0; t < NT; ++t) {
        const int cur = (t & 1) << 16;
        const int nxt = ((t + 1) & 1) << 16;
        const bool more = (t + 1 < NT);
        const char* gAs = gA + (size_t)(t + 1) * 128;
        const char* gBs = gB + (size_t)(t + 1) * 128;

        // ---------- phase 0: mi 0-1, ks 0-1 ----------
        asm volatile("s_waitcnt vmcnt(2)" ::: "memory");
        BAR;
#pragma unroll
        for (int d = 0; d < 2; ++d)
#pragma unroll
            for (int k = 0; k < 2; ++k)
                af[d][k] = *reinterpret_cast<const short8*>(lds + cur + aRowB + d * 4096 + sl[k]);
#pragma unroll
        for (int n = 0; n < 2; ++n)
#pragma unroll
            for (int k = 0; k < 2; ++k)
                bfr[n][k] = *reinterpret_cast<const short8*>(lds + cur + bRowB + n * 4096 + sl[k]);
        if (more) {
            gload_lds16(lds + nxt + 32768 + 0 * 8192 + w * 1024, gBs + 0 * 262144);
            gload_lds16(lds + nxt + 32768 + 2 * 8192 + w * 1024, gBs + 2 * 262144);
        }
        __builtin_amdgcn_s_setprio(1);
#pragma unroll
        for (int d = 0; d < 2; ++d)
#pragma unroll
            for (int n = 0; n < 2; ++n)
#pragma unroll
                for (int k = 0; k < 2; ++k)
                    acc[d][n] = __builtin_amdgcn_mfma_f32_32x32x16_bf16(
                        af[d][k], bfr[n][k], acc[d][n], 0, 0, 0);
        __builtin_amdgcn_s_setprio(0);

        // ---------- phase 1: mi 2-3, ks 0-1 ----------
        if (more) asm volatile("s_waitcnt vmcnt(2)" ::: "memory");
        else      asm volatile("s_waitcnt vmcnt(0)" ::: "memory");
        BAR;
#pragma unroll
        for (int d = 0; d < 2; ++d)
#pragma unroll
            for (int k = 0; k < 2; ++k)
                af[d][k] = *reinterpret_cast<const short8*>(lds + cur + aRowB + (2 + d) * 4096 + sl[k]);
        if (more) {
            gload_lds16(lds + nxt + 32768 + 1 * 8192 + w * 1024, gBs + 1 * 262144);
            gload_lds16(lds + nxt + 32768 + 3 * 8192 + w * 1024, gBs + 3 * 262144);
        }
        __builtin_amdgcn_s_setprio(1);
#pragma unroll
        for (int d = 0; d < 2; ++d)
#pragma unroll
            for (int n = 0; n < 2; ++n)
#pragma unroll
                for (int k = 0; k < 2; ++k)
                    acc[2 + d][n] = __builtin_amdgcn_mfma_f32_32x32x16_bf16(
                        af[d][k], bfr[n][k], acc[2 + d][n], 0, 0, 0);
        __builtin_amdgcn_s_setprio(0);

        // ---------- phase 2: mi 0-1, ks 2-3 ----------
        BAR;
#pragma unroll
        for (int d = 0; d < 2; ++d)
#pragma unroll
            for (int k = 0; k < 2; ++k)
                af[d][k] = *reinterpret_cast<const short8*>(lds + cur + aRowB + d * 4096 + sl[2 + k]);
#pragma unroll
        for (int n = 0; n < 2; ++n)
#pragma unroll
            for (int k = 0; k < 2; ++k)
                bfr[n][k] = *reinterpret_cast<const short8*>(lds + cur + bRowB + n * 4096 + sl[2 + k]);
        if (more) {
            gload_lds16(lds + nxt + 0 * 8192 + w * 1024, gAs + 0 * 262144);
            gload_lds16(lds + nxt + 2 * 8192 + w * 1024, gAs + 2 * 262144);
        }
        __builtin_amdgcn_s_setprio(1);
#pragma unroll
        for (int d = 0; d < 2; ++d)
#pragma unroll
            for (int n = 0; n < 2; ++n)
#pragma unroll
                for (int k = 0; k < 2; ++k)
                    acc[d][n] = __builtin_amdgcn_mfma_f32_32x32x16_bf16(
                        af[d][k], bfr[n][k], acc[d][n], 0, 0, 0);
        __builtin_amdgcn_s_setprio(0);

        // ---------- phase 3: mi 2-3, ks 2-3 ----------
        BAR;
#pragma unroll
        for (int d = 0; d < 2; ++d)
#pragma unroll
            for (int k = 0; k < 2; ++k)
                af[d][k] = *reinterpret_cast<const short8*>(lds + cur + aRowB + (2 + d) * 4096 + sl[2 + k]);
        if (more) {
            gload_lds16(lds + nxt + 1 * 8192 + w * 1024, gAs + 1 * 262144);
            gload_lds16(lds + nxt + 3 * 8192 + w * 1024, gAs + 3 * 262144);
        }
        __builtin_amdgcn_s_setprio(1);
#pragma unroll
        for (int d = 0; d < 2; ++d)
#pragma unroll
            for (int n = 0; n < 2; ++n)
#pragma unroll
                for (int k = 0; k < 2; ++k)
                    acc[2 + d][n] = __builtin_amdgcn_mfma_f32_32x32x16_bf16(
                        af[d][k], bfr[n][k], acc[2 + d][n], 0, 0, 0);
        __builtin_amdgcn_s_setprio(0);
    }

    // ---- epilogue: 32x32 C/D: col = lane&31, row = (r&3)+8*(r>>2)+4*(lane>>5)
    const int c_col = lane & 31;
    const int c_r4  = (lane >> 5) * 4;
#pragma unroll
    for (int mi = 0; mi < 4; ++mi)
#pragma unroll
        for (int ni = 0; ni < 2; ++ni) {
            const int rb = bm * 256 + wr * 128 + mi * 32 + c_r4;
            const int cb = bn * 256 + wc * 64 + ni * 32 + c_col;
#pragma unroll
            for (int r = 0; r < 16; ++r)
                O[(size_t)(rb + (r & 3) + 8 * (r >> 2)) * NDIM + cb] = acc[mi][ni][r];
        }
}

// ---------------- fallback: round-1 fused kernel ----------------
__global__ __launch_bounds__(256, 2) void binlin_fused(
        const float* __restrict__ X, const float* __restrict__ W,
        float* __restrict__ O) {
    const int tid = threadIdx.x;
    const int lane = tid & 63;
    const int wave = tid >> 6;
    const int wr = wave >> 1, wc = wave & 1;
    const int NWG = (MDIM / 128) * (NDIM / 128);
    int id = blockIdx.x;
    int swz = (id & 7) * (NWG >> 3) + (id >> 3);
    const int bm = swz >> 4, bn = swz & 15;

    __shared__ __align__(16) unsigned short As[128][40];
    __shared__ __align__(16) unsigned short Bs[128][40];

    const int rA = tid >> 3, kA = (tid & 7) * 4;
    const float* aPtr = X + (size_t)(bm * 128 + rA) * KDIM + kA;
    const int nB = (tid & 31) * 4, kB = (tid >> 5) * 4;
    const float* bPtr = W + (size_t)kB * NDIM + (size_t)bn * 128 + nB;

    float4v aReg[4], bReg[4];
#pragma unroll
    for (int p = 0; p < 4; ++p)
        aReg[p] = *reinterpret_cast<const float4v*>(aPtr + (size_t)(32 * p) * KDIM);
#pragma unroll
    for (int dk = 0; dk < 4; ++dk)
        bReg[dk] = *reinterpret_cast<const float4v*>(bPtr + (size_t)dk * NDIM);

    f32x4 acc[4][4];
#pragma unroll
    for (int i = 0; i < 4; ++i)
#pragma unroll
        for (int j = 0; j < 4; ++j) {
            acc[i][j][0] = 0.f; acc[i][j][1] = 0.f; acc[i][j][2] = 0.f; acc[i][j][3] = 0.f;
        }

    const int r16 = lane & 15, g8 = (lane >> 4) * 8;
    for (int kt = 0; kt < KDIM; kt += 32) {
#pragma unroll
        for (int p = 0; p < 4; ++p) {
            ushort4v v;
            v[0] = f2bf(aReg[p][0]); v[1] = f2bf(aReg[p][1]);
            v[2] = f2bf(aReg[p][2]); v[3] = f2bf(aReg[p][3]);
            *reinterpret_cast<ushort4v*>(&As[rA + 32 * p][kA]) = v;
        }
        unsigned short bb[4][4];
#pragma unroll
        for (int dk = 0; dk < 4; ++dk)
#pragma unroll
            for (int dn = 0; dn < 4; ++dn)
                bb[dn][dk] = (bReg[dk][dn] > 0.0f) ? (unsigned short)0x3F80u
                                                   : (unsigned short)0u;
#pragma unroll
        for (int dn = 0; dn < 4; ++dn) {
            ushort4v v;
            v[0] = bb[dn][0]; v[1] = bb[dn][1]; v[2] = bb[dn][2]; v[3] = bb[dn][3];
            *reinterpret_cast<ushort4v*>(&Bs[nB + dn][kB]) = v;
        }
        __syncthreads();
        if (kt + 32 < KDIM) {
#pragma unroll
            for (int p = 0; p < 4; ++p)
                aReg[p] = *reinterpret_cast<const float4v*>(
                    aPtr + (size_t)(32 * p) * KDIM + (kt + 32));
#pragma unroll
            for (int dk = 0; dk < 4; ++dk)
                bReg[dk] = *reinterpret_cast<const float4v*>(
                    bPtr + (size_t)(kt + 32 + dk) * NDIM);
        }
        short8 af[4], bf[4];
#pragma unroll
        for (int mi = 0; mi < 4; ++mi)
            af[mi] = *reinterpret_cast<const short8*>(&As[wr * 64 + mi * 16 + r16][g8]);
#pragma unroll
        for (int ni = 0; ni < 4; ++ni)
            bf[ni] = *reinterpret_cast<const short8*>(&Bs[wc * 64 + ni * 16 + r16][g8]);
#pragma unroll
        for (int mi = 0; mi < 4; ++mi)
#pragma unroll
            for (int ni = 0; ni < 4; ++ni)
                acc[mi][ni] = __builtin_amdgcn_mfma_f32_16x16x32_bf16(
                    af[mi], bf[ni], acc[mi][ni], 0, 0, 0);
        __syncthreads();
    }

    const int orow0 = bm * 128 + wr * 64 + (lane >> 4) * 4;
    const int ocol0 = bn * 128 + wc * 64 + r16;
#pragma unroll
    for (int mi = 0; mi < 4; ++mi)
#pragma unroll
        for (int ni = 0; ni < 4; ++ni)
#pragma unroll
            for (int r = 0; r < 4; ++r)
                O[(size_t)(orow0 + mi * 16 + r) * NDIM + ocol0 + ni * 16] =
                    acc[mi][ni][r];
}

extern "C" void kernel_launch(void* const* d_in, const int* in_sizes, int n_in,
                              void* d_out, int out_size, void* d_ws, size_t ws_size,
                              hipStream_t stream) {
    const float* X = (const float*)d_in[0];
    const float* W = (const float*)d_in[1];
    float* O = (float*)d_out;
    (void)in_sizes; (void)n_in; (void)out_size;

    const size_t xb_elems = (size_t)MDIM * KDIM;
    const size_t wt_elems = (size_t)NDIM * KDIM;
    const size_t need = (xb_elems + wt_elems) * sizeof(unsigned short);

    if (ws_size >= need) {
        unsigned short* Xb = (unsigned short*)d_ws;
        unsigned short* Wt = Xb + xb_elems;
        hipFuncSetAttribute((const void*)gemm_32,
                            hipFuncAttributeMaxDynamicSharedMemorySize, 131072);
        cvt_x<<<dim3(MDIM * KDIM / (256 * 8)), dim3(256), 0, stream>>>(X, Xb);
        bin_w<<<dim3((KDIM / 64) * (NDIM / 64)), dim3(256), 0, stream>>>(W, Wt);
        gemm_32<<<dim3((MDIM / 256) * (NDIM / 256)), dim3(512), 131072, stream>>>(Xb, Wt, O);
    } else {
        binlin_fused<<<dim3((MDIM / 128) * (NDIM / 128)), dim3(256), 0, stream>>>(X, W, O);
    }
}

// Round 6
// 57.358 us; speedup vs baseline: 1.5588x; 1.5588x over previous
//
#include <hip/hip_runtime.h>

// BinaryLinear int8 path:
//   cvt_xq : X f32 -> i8 per-row symmetric quant (scale = rowmax/127) + Sc[row]
//   bin_w8 : W f32 (KxN) -> {0,1} i8, transposed to NxK
//   gemm_i8: 256x256 tile, BK=128 (i8 bytes), 8 waves, dbuf 128KB LDS,
//            4-phase counted-vmcnt pipeline (round-3 proven skeleton),
//            XOR swizzle, mfma_i32_16x16x64_i8, f32 dequant epilogue.
// Fallback: round-1 fused bf16 kernel if ws too small.

#define MDIM 8192
#define NDIM 2048
#define KDIM 2048
#define NT   (KDIM / 128)         // 16 K-tiles of 128 i8
#define CH   (64 * KDIM)          // global chunk stride: 64 rows * 2048 B

typedef __attribute__((ext_vector_type(8))) short short8;
typedef __attribute__((ext_vector_type(4))) float float4v;
typedef __attribute__((ext_vector_type(4))) float f32x4;
typedef __attribute__((ext_vector_type(4))) int int4v;
typedef __attribute__((ext_vector_type(4))) unsigned short ushort4v;
typedef __attribute__((ext_vector_type(8))) unsigned short ushort8v;

__device__ __forceinline__ unsigned short f2bf(float f) {
    union { float f; unsigned u; } v; v.f = f;
    unsigned r = v.u + 0x7FFFu + ((v.u >> 16) & 1u);
    return (unsigned short)(r >> 16);
}

__device__ __forceinline__ void gload_lds16(void* l, const void* g) {
    __builtin_amdgcn_global_load_lds(
        (const __attribute__((address_space(1))) unsigned int*)g,
        (__attribute__((address_space(3))) unsigned int*)l,
        16, 0, 0);
}

#define FENCE asm volatile("" ::: "memory")
#define BAR do { FENCE; __builtin_amdgcn_s_barrier(); FENCE; } while (0)

// ---------------- pass 1a: X -> i8 per-row quant ----------------
__global__ __launch_bounds__(256) void cvt_xq(const float* __restrict__ X,
                                              signed char* __restrict__ Xq,
                                              float* __restrict__ Sc) {
    const int row = blockIdx.x;
    const int t = threadIdx.x;
    const float* xr = X + (size_t)row * KDIM + t * 8;
    float4v a = *reinterpret_cast<const float4v*>(xr);
    float4v b = *reinterpret_cast<const float4v*>(xr + 4);
    float m = fabsf(a[0]);
    m = fmaxf(m, fabsf(a[1])); m = fmaxf(m, fabsf(a[2])); m = fmaxf(m, fabsf(a[3]));
    m = fmaxf(m, fabsf(b[0])); m = fmaxf(m, fabsf(b[1]));
    m = fmaxf(m, fabsf(b[2])); m = fmaxf(m, fabsf(b[3]));
#pragma unroll
    for (int off = 32; off; off >>= 1)
        m = fmaxf(m, __shfl_xor(m, off));
    __shared__ float wm[4];
    if ((t & 63) == 0) wm[t >> 6] = m;
    __syncthreads();
    const float s = fmaxf(fmaxf(wm[0], wm[1]), fmaxf(wm[2], wm[3]));
    const float inv = (s > 0.f) ? 127.0f / s : 0.f;

    int q[8];
    q[0] = __float2int_rn(a[0] * inv); q[1] = __float2int_rn(a[1] * inv);
    q[2] = __float2int_rn(a[2] * inv); q[3] = __float2int_rn(a[3] * inv);
    q[4] = __float2int_rn(b[0] * inv); q[5] = __float2int_rn(b[1] * inv);
    q[6] = __float2int_rn(b[2] * inv); q[7] = __float2int_rn(b[3] * inv);
    unsigned lo = (q[0] & 255) | ((q[1] & 255) << 8) | ((q[2] & 255) << 16) | ((unsigned)(q[3] & 255) << 24);
    unsigned hi = (q[4] & 255) | ((q[5] & 255) << 8) | ((q[6] & 255) << 16) | ((unsigned)(q[7] & 255) << 24);
    unsigned* dst = (unsigned*)(Xq + (size_t)row * KDIM + t * 8);
    dst[0] = lo; dst[1] = hi;
    if (t == 0) Sc[row] = s * (1.0f / 127.0f);
}

// ---------------- pass 1b: binarize + transpose W -> i8 {0,1} ----------------
__global__ __launch_bounds__(256) void bin_w8(const float* __restrict__ W,
                                              signed char* __restrict__ Wt) {
    __shared__ __align__(16) signed char T[64][80];
    const int t = threadIdx.x;
    const int k0 = (blockIdx.x >> 5) * 64;
    const int n0 = (blockIdx.x & 31) * 64;
    const int kr = t >> 4;
    const int nc = (t & 15) * 4;
#pragma unroll
    for (int rr = 0; rr < 4; ++rr) {
        int k = k0 + rr * 16 + kr;
        float4v w4 = *reinterpret_cast<const float4v*>(W + (size_t)k * NDIM + n0 + nc);
#pragma unroll
        for (int c = 0; c < 4; ++c)
            T[nc + c][rr * 16 + kr] = (w4[c] > 0.0f) ? (signed char)1 : (signed char)0;
    }
    __syncthreads();
    const int row = t >> 2, ch = t & 3;
    int4v v = *reinterpret_cast<const int4v*>(&T[row][ch * 16]);
    *reinterpret_cast<int4v*>(Wt + (size_t)(n0 + row) * KDIM + k0 + ch * 16) = v;
}

// ---------------- pass 2: 256x256 i8 GEMM (round-3 skeleton) ----------------
// LDS per buffer (64 KB): A [256 rows][128 B] at +0, B at +32768; 16B slot s
// of row r holds global slot s^(r&7) (via pre-swizzled source). Chunk c
// (8 KB) = 64 rows. Wave tile 128x64 = 8mi x 4ni 16x16 frags; per tile
// 2 k-steps (K=64 each). Stages for t+1: ph0 B0,B2 | ph1 B1,B3 | ph2 A0,A2
// | ph3 A1,A3. Waits: ph0 vmcnt(2); ph1 more?vmcnt(2):vmcnt(0).
__global__ __launch_bounds__(512, 1) void gemm_i8(const signed char* __restrict__ A,
                                                  const signed char* __restrict__ Bt,
                                                  const float* __restrict__ Sc,
                                                  float* __restrict__ O) {
    extern __shared__ char lds[];
    const int tid  = threadIdx.x;
    const int lane = tid & 63;
    const int w    = tid >> 6;       // 0..7
    const int wr   = w >> 2;         // 0..1
    const int wc   = w & 3;          // 0..3

    int id  = blockIdx.x;            // 256 blocks, %8==0 -> bijective
    int swz = (id & 7) * 32 + (id >> 3);
    const int bm = swz >> 3;         // 0..31
    const int bn = swz & 7;          // 0..7

    // staging source: row = w*8 + l3, pre-swizzled slot (l7 ^ l3)
    const int l3 = lane >> 3, l7 = lane & 7;
    const int srcOff = (w * 8 + l3) * KDIM + ((l7 ^ l3) << 4);
    const char* gA = (const char*)A + (size_t)(bm * 256) * KDIM + srcOff;
    const char* gB = (const char*)Bt + (size_t)(bn * 256) * KDIM + srcOff;

    // fragment read constants: lane l -> row l&15, 16 k-bytes at slot l>>4
    const int fr = lane & 15, fg = lane >> 4;
    const int se0 = ((fg)     ^ (fr & 7)) << 4;   // ks0: slots 0-3
    const int se1 = ((4 + fg) ^ (fr & 7)) << 4;   // ks1: slots 4-7
    const int aRd = (wr * 128 + fr) * 128;        // + buf + mi*2048 + se
    const int bRd = 32768 + (wc * 64 + fr) * 128; // + buf + ni*2048 + se

    int4v acc[8][4];
#pragma unroll
    for (int i = 0; i < 8; ++i)
#pragma unroll
        for (int j = 0; j < 4; ++j) {
            acc[i][j][0] = 0; acc[i][j][1] = 0; acc[i][j][2] = 0; acc[i][j][3] = 0;
        }

    // prologue: stage tile 0 (steady order), drain, barrier
    gload_lds16(lds + 32768 + 0 * 8192 + w * 1024, gB + 0 * CH);
    gload_lds16(lds + 32768 + 2 * 8192 + w * 1024, gB + 2 * CH);
    gload_lds16(lds + 32768 + 1 * 8192 + w * 1024, gB + 1 * CH);
    gload_lds16(lds + 32768 + 3 * 8192 + w * 1024, gB + 3 * CH);
    gload_lds16(lds + 0 * 8192 + w * 1024, gA + 0 * CH);
    gload_lds16(lds + 2 * 8192 + w * 1024, gA + 2 * CH);
    gload_lds16(lds + 1 * 8192 + w * 1024, gA + 1 * CH);
    gload_lds16(lds + 3 * 8192 + w * 1024, gA + 3 * CH);
    asm volatile("s_waitcnt vmcnt(0)" ::: "memory");
    BAR;

    int4v af[4], bfr[4];

    for (int t = 0; t < NT; ++t) {
        const int cur = (t & 1) << 16;
        const int nxt = ((t + 1) & 1) << 16;
        const bool more = (t + 1 < NT);
        const char* gAs = gA + (size_t)(t + 1) * 128;
        const char* gBs = gB + (size_t)(t + 1) * 128;

        // ---------- phase 0: mi 0-3, ks0 ----------
        asm volatile("s_waitcnt vmcnt(2)" ::: "memory");
        BAR;
#pragma unroll
        for (int j = 0; j < 4; ++j)
            af[j] = *reinterpret_cast<const int4v*>(lds + cur + aRd + j * 2048 + se0);
#pragma unroll
        for (int n = 0; n < 4; ++n)
            bfr[n] = *reinterpret_cast<const int4v*>(lds + cur + bRd + n * 2048 + se0);
        if (more) {
            gload_lds16(lds + nxt + 32768 + 0 * 8192 + w * 1024, gBs + 0 * CH);
            gload_lds16(lds + nxt + 32768 + 2 * 8192 + w * 1024, gBs + 2 * CH);
        }
        __builtin_amdgcn_s_setprio(1);
#pragma unroll
        for (int mi = 0; mi < 4; ++mi)
#pragma unroll
            for (int ni = 0; ni < 4; ++ni)
                acc[mi][ni] = __builtin_amdgcn_mfma_i32_16x16x64_i8(
                    af[mi], bfr[ni], acc[mi][ni], 0, 0, 0);
        __builtin_amdgcn_s_setprio(0);

        // ---------- phase 1: mi 4-7, ks0 ----------
        if (more) asm volatile("s_waitcnt vmcnt(2)" ::: "memory");
        else      asm volatile("s_waitcnt vmcnt(0)" ::: "memory");
        BAR;
#pragma unroll
        for (int j = 0; j < 4; ++j)
            af[j] = *reinterpret_cast<const int4v*>(lds + cur + aRd + (4 + j) * 2048 + se0);
        if (more) {
            gload_lds16(lds + nxt + 32768 + 1 * 8192 + w * 1024, gBs + 1 * CH);
            gload_lds16(lds + nxt + 32768 + 3 * 8192 + w * 1024, gBs + 3 * CH);
        }
        __builtin_amdgcn_s_setprio(1);
#pragma unroll
        for (int mi = 0; mi < 4; ++mi)
#pragma unroll
            for (int ni = 0; ni < 4; ++ni)
                acc[4 + mi][ni] = __builtin_amdgcn_mfma_i32_16x16x64_i8(
                    af[mi], bfr[ni], acc[4 + mi][ni], 0, 0, 0);
        __builtin_amdgcn_s_setprio(0);

        // ---------- phase 2: mi 0-3, ks1 ----------
        BAR;
#pragma unroll
        for (int j = 0; j < 4; ++j)
            af[j] = *reinterpret_cast<const int4v*>(lds + cur + aRd + j * 2048 + se1);
#pragma unroll
        for (int n = 0; n < 4; ++n)
            bfr[n] = *reinterpret_cast<const int4v*>(lds + cur + bRd + n * 2048 + se1);
        if (more) {
            gload_lds16(lds + nxt + 0 * 8192 + w * 1024, gAs + 0 * CH);
            gload_lds16(lds + nxt + 2 * 8192 + w * 1024, gAs + 2 * CH);
        }
        __builtin_amdgcn_s_setprio(1);
#pragma unroll
        for (int mi = 0; mi < 4; ++mi)
#pragma unroll
            for (int ni = 0; ni < 4; ++ni)
                acc[mi][ni] = __builtin_amdgcn_mfma_i32_16x16x64_i8(
                    af[mi], bfr[ni], acc[mi][ni], 0, 0, 0);
        __builtin_amdgcn_s_setprio(0);

        // ---------- phase 3: mi 4-7, ks1 ----------
        BAR;
#pragma unroll
        for (int j = 0; j < 4; ++j)
            af[j] = *reinterpret_cast<const int4v*>(lds + cur + aRd + (4 + j) * 2048 + se1);
        if (more) {
            gload_lds16(lds + nxt + 1 * 8192 + w * 1024, gAs + 1 * CH);
            gload_lds16(lds + nxt + 3 * 8192 + w * 1024, gAs + 3 * CH);
        }
        __builtin_amdgcn_s_setprio(1);
#pragma unroll
        for (int mi = 0; mi < 4; ++mi)
#pragma unroll
            for (int ni = 0; ni < 4; ++ni)
                acc[4 + mi][ni] = __builtin_amdgcn_mfma_i32_16x16x64_i8(
                    af[mi], bfr[ni], acc[4 + mi][ni], 0, 0, 0);
        __builtin_amdgcn_s_setprio(0);
    }

    // ---- epilogue: C/D col = lane&15, row = 4*(lane>>4) + reg; dequant ----
    const int orow0 = bm * 256 + wr * 128 + fg * 4;
    const int ocol0 = bn * 256 + wc * 64 + fr;
#pragma unroll
    for (int mi = 0; mi < 8; ++mi)
#pragma unroll
        for (int r = 0; r < 4; ++r) {
            const int row = orow0 + mi * 16 + r;
            const float s = Sc[row];
            float* op = O + (size_t)row * NDIM + ocol0;
#pragma unroll
            for (int ni = 0; ni < 4; ++ni)
                op[ni * 16] = s * (float)acc[mi][ni][r];
        }
}

// ---------------- fallback: round-1 fused bf16 kernel ----------------
__global__ __launch_bounds__(256, 2) void binlin_fused(
        const float* __restrict__ X, const float* __restrict__ W,
        float* __restrict__ O) {
    const int tid = threadIdx.x;
    const int lane = tid & 63;
    const int wave = tid >> 6;
    const int wr = wave >> 1, wc = wave & 1;
    const int NWG = (MDIM / 128) * (NDIM / 128);
    int id = blockIdx.x;
    int swz = (id & 7) * (NWG >> 3) + (id >> 3);
    const int bm = swz >> 4, bn = swz & 15;

    __shared__ __align__(16) unsigned short As[128][40];
    __shared__ __align__(16) unsigned short Bs[128][40];

    const int rA = tid >> 3, kA = (tid & 7) * 4;
    const float* aPtr = X + (size_t)(bm * 128 + rA) * KDIM + kA;
    const int nB = (tid & 31) * 4, kB = (tid >> 5) * 4;
    const float* bPtr = W + (size_t)kB * NDIM + (size_t)bn * 128 + nB;

    float4v aReg[4], bReg[4];
#pragma unroll
    for (int p = 0; p < 4; ++p)
        aReg[p] = *reinterpret_cast<const float4v*>(aPtr + (size_t)(32 * p) * KDIM);
#pragma unroll
    for (int dk = 0; dk < 4; ++dk)
        bReg[dk] = *reinterpret_cast<const float4v*>(bPtr + (size_t)dk * NDIM);

    f32x4 acc[4][4];
#pragma unroll
    for (int i = 0; i < 4; ++i)
#pragma unroll
        for (int j = 0; j < 4; ++j) {
            acc[i][j][0] = 0.f; acc[i][j][1] = 0.f; acc[i][j][2] = 0.f; acc[i][j][3] = 0.f;
        }

    const int r16 = lane & 15, g8 = (lane >> 4) * 8;
    for (int kt = 0; kt < KDIM; kt += 32) {
#pragma unroll
        for (int p = 0; p < 4; ++p) {
            ushort4v v;
            v[0] = f2bf(aReg[p][0]); v[1] = f2bf(aReg[p][1]);
            v[2] = f2bf(aReg[p][2]); v[3] = f2bf(aReg[p][3]);
            *reinterpret_cast<ushort4v*>(&As[rA + 32 * p][kA]) = v;
        }
        unsigned short bb[4][4];
#pragma unroll
        for (int dk = 0; dk < 4; ++dk)
#pragma unroll
            for (int dn = 0; dn < 4; ++dn)
                bb[dn][dk] = (bReg[dk][dn] > 0.0f) ? (unsigned short)0x3F80u
                                                   : (unsigned short)0u;
#pragma unroll
        for (int dn = 0; dn < 4; ++dn) {
            ushort4v v;
            v[0] = bb[dn][0]; v[1] = bb[dn][1]; v[2] = bb[dn][2]; v[3] = bb[dn][3];
            *reinterpret_cast<ushort4v*>(&Bs[nB + dn][kB]) = v;
        }
        __syncthreads();
        if (kt + 32 < KDIM) {
#pragma unroll
            for (int p = 0; p < 4; ++p)
                aReg[p] = *reinterpret_cast<const float4v*>(
                    aPtr + (size_t)(32 * p) * KDIM + (kt + 32));
#pragma unroll
            for (int dk = 0; dk < 4; ++dk)
                bReg[dk] = *reinterpret_cast<const float4v*>(
                    bPtr + (size_t)(kt + 32 + dk) * NDIM);
        }
        short8 af[4], bf[4];
#pragma unroll
        for (int mi = 0; mi < 4; ++mi)
            af[mi] = *reinterpret_cast<const short8*>(&As[wr * 64 + mi * 16 + r16][g8]);
#pragma unroll
        for (int ni = 0; ni < 4; ++ni)
            bf[ni] = *reinterpret_cast<const short8*>(&Bs[wc * 64 + ni * 16 + r16][g8]);
#pragma unroll
        for (int mi = 0; mi < 4; ++mi)
#pragma unroll
            for (int ni = 0; ni < 4; ++ni)
                acc[mi][ni] = __builtin_amdgcn_mfma_f32_16x16x32_bf16(
                    af[mi], bf[ni], acc[mi][ni], 0, 0, 0);
        __syncthreads();
    }

    const int orow0 = bm * 128 + wr * 64 + (lane >> 4) * 4;
    const int ocol0 = bn * 128 + wc * 64 + r16;
#pragma unroll
    for (int mi = 0; mi < 4; ++mi)
#pragma unroll
        for (int ni = 0; ni < 4; ++ni)
#pragma unroll
            for (int r = 0; r < 4; ++r)
                O[(size_t)(orow0 + mi * 16 + r) * NDIM + ocol0 + ni * 16] =
                    acc[mi][ni][r];
}

extern "C" void kernel_launch(void* const* d_in, const int* in_sizes, int n_in,
                              void* d_out, int out_size, void* d_ws, size_t ws_size,
                              hipStream_t stream) {
    const float* X = (const float*)d_in[0];
    const float* W = (const float*)d_in[1];
    float* O = (float*)d_out;
    (void)in_sizes; (void)n_in; (void)out_size;

    const size_t xq_bytes = (size_t)MDIM * KDIM;          // 16 MB
    const size_t wt_bytes = (size_t)NDIM * KDIM;          // 4 MB
    const size_t sc_bytes = (size_t)MDIM * sizeof(float); // 32 KB
    const size_t need = xq_bytes + wt_bytes + sc_bytes;

    if (ws_size >= need) {
        signed char* Xq = (signed char*)d_ws;
        signed char* Wt = Xq + xq_bytes;
        float* Sc = (float*)(Wt + wt_bytes);
        hipFuncSetAttribute((const void*)gemm_i8,
                            hipFuncAttributeMaxDynamicSharedMemorySize, 131072);
        cvt_xq<<<dim3(MDIM), dim3(256), 0, stream>>>(X, Xq, Sc);
        bin_w8<<<dim3((KDIM / 64) * (NDIM / 64)), dim3(256), 0, stream>>>(W, Wt);
        gemm_i8<<<dim3((MDIM / 256) * (NDIM / 256)), dim3(512), 131072, stream>>>(Xq, Wt, Sc, O);
    } else {
        binlin_fused<<<dim3((MDIM / 128) * (NDIM / 128)), dim3(256), 0, stream>>>(X, W, O);
    }
}

// Round 7
// 55.798 us; speedup vs baseline: 1.6024x; 1.0280x over previous
//
#include <hip/hip_runtime.h>

// BinaryLinear int8 path (round 7):
//   prep   : fused {X f32 -> i8 per-row quant + Sc}  and  {W -> {0,1} i8, NxK}
//   gemm_i8: 256x256 tile, BK=128 i8, 8 waves, dbuf 128KB LDS,
//            2-phase counted-vmcnt pipeline (halved barriers vs round-6),
//            XOR swizzle, mfma_i32_16x16x64_i8, f32 dequant epilogue.
// Fallback: round-1 fused bf16 kernel if ws too small.

#define MDIM 8192
#define NDIM 2048
#define KDIM 2048
#define NT   (KDIM / 128)         // 16 K-tiles of 128 i8
#define CH   (64 * KDIM)          // global chunk stride: 64 rows * 2048 B

typedef __attribute__((ext_vector_type(8))) short short8;
typedef __attribute__((ext_vector_type(4))) float float4v;
typedef __attribute__((ext_vector_type(4))) float f32x4;
typedef __attribute__((ext_vector_type(4))) int int4v;
typedef __attribute__((ext_vector_type(4))) unsigned short ushort4v;
typedef __attribute__((ext_vector_type(8))) unsigned short ushort8v;

__device__ __forceinline__ unsigned short f2bf(float f) {
    union { float f; unsigned u; } v; v.f = f;
    unsigned r = v.u + 0x7FFFu + ((v.u >> 16) & 1u);
    return (unsigned short)(r >> 16);
}

__device__ __forceinline__ void gload_lds16(void* l, const void* g) {
    __builtin_amdgcn_global_load_lds(
        (const __attribute__((address_space(1))) unsigned int*)g,
        (__attribute__((address_space(3))) unsigned int*)l,
        16, 0, 0);
}

#define FENCE asm volatile("" ::: "memory")
#define BAR do { FENCE; __builtin_amdgcn_s_barrier(); FENCE; } while (0)

// ---------------- pass 1 (fused): quantize X rows + binarize/transpose W ----
// blocks [0, MDIM)            : X row quant (256 thr, 8 f32/thr)
// blocks [MDIM, MDIM+1024)    : W 64x64 binarize+transpose tiles
__global__ __launch_bounds__(256) void prep(const float* __restrict__ X,
                                            const float* __restrict__ W,
                                            signed char* __restrict__ Xq,
                                            signed char* __restrict__ Wt,
                                            float* __restrict__ Sc) {
    __shared__ __align__(16) signed char T[64][80];
    __shared__ float wm[4];
    const int t = threadIdx.x;
    const int bid = blockIdx.x;

    if (bid < MDIM) {
        // ---- X quant ----
        const int row = bid;
        const float* xr = X + (size_t)row * KDIM + t * 8;
        float4v a = *reinterpret_cast<const float4v*>(xr);
        float4v b = *reinterpret_cast<const float4v*>(xr + 4);
        float m = fabsf(a[0]);
        m = fmaxf(m, fabsf(a[1])); m = fmaxf(m, fabsf(a[2])); m = fmaxf(m, fabsf(a[3]));
        m = fmaxf(m, fabsf(b[0])); m = fmaxf(m, fabsf(b[1]));
        m = fmaxf(m, fabsf(b[2])); m = fmaxf(m, fabsf(b[3]));
#pragma unroll
        for (int off = 32; off; off >>= 1)
            m = fmaxf(m, __shfl_xor(m, off));
        if ((t & 63) == 0) wm[t >> 6] = m;
        __syncthreads();
        const float s = fmaxf(fmaxf(wm[0], wm[1]), fmaxf(wm[2], wm[3]));
        const float inv = (s > 0.f) ? 127.0f / s : 0.f;

        int q[8];
        q[0] = __float2int_rn(a[0] * inv); q[1] = __float2int_rn(a[1] * inv);
        q[2] = __float2int_rn(a[2] * inv); q[3] = __float2int_rn(a[3] * inv);
        q[4] = __float2int_rn(b[0] * inv); q[5] = __float2int_rn(b[1] * inv);
        q[6] = __float2int_rn(b[2] * inv); q[7] = __float2int_rn(b[3] * inv);
        unsigned lo = (q[0] & 255) | ((q[1] & 255) << 8) | ((q[2] & 255) << 16) | ((unsigned)(q[3] & 255) << 24);
        unsigned hi = (q[4] & 255) | ((q[5] & 255) << 8) | ((q[6] & 255) << 16) | ((unsigned)(q[7] & 255) << 24);
        unsigned* dst = (unsigned*)(Xq + (size_t)row * KDIM + t * 8);
        dst[0] = lo; dst[1] = hi;
        if (t == 0) Sc[row] = s * (1.0f / 127.0f);
    } else {
        // ---- W binarize + transpose ----
        const int wb = bid - MDIM;
        const int k0 = (wb >> 5) * 64;
        const int n0 = (wb & 31) * 64;
        const int kr = t >> 4;
        const int nc = (t & 15) * 4;
#pragma unroll
        for (int rr = 0; rr < 4; ++rr) {
            int k = k0 + rr * 16 + kr;
            float4v w4 = *reinterpret_cast<const float4v*>(W + (size_t)k * NDIM + n0 + nc);
#pragma unroll
            for (int c = 0; c < 4; ++c)
                T[nc + c][rr * 16 + kr] = (w4[c] > 0.0f) ? (signed char)1 : (signed char)0;
        }
        __syncthreads();
        const int row = t >> 2, ch = t & 3;
        int4v v = *reinterpret_cast<const int4v*>(&T[row][ch * 16]);
        *reinterpret_cast<int4v*>(Wt + (size_t)(n0 + row) * KDIM + k0 + ch * 16) = v;
    }
}

// ---------------- pass 2: 256x256 i8 GEMM, 2-phase pipeline ----------------
// LDS per buffer (64 KB): A [256 rows][128 B] at +0, B at +32768; 16B slot s
// of row r holds global slot s^(r&7) (via pre-swizzled source). Chunk c
// (8 KB) = 64 rows. Wave tile 128x64 = 8mi x 4ni 16x16 frags, 2 ks-steps.
// ph0: mi 0-3 x {ks0,ks1} (needs all B(t) + A chunks {0,2});
//      stages B(t+1) x4. wait vmcnt(2).
// ph1: mi 4-7 x {ks0,ks1} (needs A chunks {1,3}); B frags reused from ph0;
//      stages A(t+1) in order A0,A2,A1,A3. wait vmcnt(4) (last tile: 0).
__global__ __launch_bounds__(512, 1) void gemm_i8(const signed char* __restrict__ A,
                                                  const signed char* __restrict__ Bt,
                                                  const float* __restrict__ Sc,
                                                  float* __restrict__ O) {
    extern __shared__ char lds[];
    const int tid  = threadIdx.x;
    const int lane = tid & 63;
    const int w    = tid >> 6;       // 0..7
    const int wr   = w >> 2;         // 0..1
    const int wc   = w & 3;          // 0..3

    int id  = blockIdx.x;            // 256 blocks, %8==0 -> bijective
    int swz = (id & 7) * 32 + (id >> 3);
    const int bm = swz >> 3;         // 0..31
    const int bn = swz & 7;          // 0..7

    // staging source: row = w*8 + l3, pre-swizzled slot (l7 ^ l3)
    const int l3 = lane >> 3, l7 = lane & 7;
    const int srcOff = (w * 8 + l3) * KDIM + ((l7 ^ l3) << 4);
    const char* gA = (const char*)A + (size_t)(bm * 256) * KDIM + srcOff;
    const char* gB = (const char*)Bt + (size_t)(bn * 256) * KDIM + srcOff;

    // fragment read constants: lane l -> row l&15, 16 k-bytes at slot l>>4
    const int fr = lane & 15, fg = lane >> 4;
    const int se0 = ((fg)     ^ (fr & 7)) << 4;   // ks0: slots 0-3
    const int se1 = ((4 + fg) ^ (fr & 7)) << 4;   // ks1: slots 4-7
    const int aRd = (wr * 128 + fr) * 128;        // + buf + mi*2048 + se
    const int bRd = 32768 + (wc * 64 + fr) * 128; // + buf + ni*2048 + se

    int4v acc[8][4];
#pragma unroll
    for (int i = 0; i < 8; ++i)
#pragma unroll
        for (int j = 0; j < 4; ++j) {
            acc[i][j][0] = 0; acc[i][j][1] = 0; acc[i][j][2] = 0; acc[i][j][3] = 0;
        }

    // prologue: stage tile 0 (steady order), drain, barrier
    gload_lds16(lds + 32768 + 0 * 8192 + w * 1024, gB + 0 * CH);
    gload_lds16(lds + 32768 + 2 * 8192 + w * 1024, gB + 2 * CH);
    gload_lds16(lds + 32768 + 1 * 8192 + w * 1024, gB + 1 * CH);
    gload_lds16(lds + 32768 + 3 * 8192 + w * 1024, gB + 3 * CH);
    gload_lds16(lds + 0 * 8192 + w * 1024, gA + 0 * CH);
    gload_lds16(lds + 2 * 8192 + w * 1024, gA + 2 * CH);
    gload_lds16(lds + 1 * 8192 + w * 1024, gA + 1 * CH);
    gload_lds16(lds + 3 * 8192 + w * 1024, gA + 3 * CH);
    asm volatile("s_waitcnt vmcnt(0)" ::: "memory");
    BAR;

    int4v af[4][2], bfr[4][2];

    for (int t = 0; t < NT; ++t) {
        const int cur = (t & 1) << 16;
        const int nxt = ((t + 1) & 1) << 16;
        const bool more = (t + 1 < NT);
        const char* gAs = gA + (size_t)(t + 1) * 128;
        const char* gBs = gB + (size_t)(t + 1) * 128;

        // ---------- phase 0: mi 0-3, ks0+ks1 ----------
        asm volatile("s_waitcnt vmcnt(2)" ::: "memory");
        BAR;
#pragma unroll
        for (int j = 0; j < 4; ++j) {
            af[j][0] = *reinterpret_cast<const int4v*>(lds + cur + aRd + j * 2048 + se0);
            af[j][1] = *reinterpret_cast<const int4v*>(lds + cur + aRd + j * 2048 + se1);
        }
#pragma unroll
        for (int n = 0; n < 4; ++n) {
            bfr[n][0] = *reinterpret_cast<const int4v*>(lds + cur + bRd + n * 2048 + se0);
            bfr[n][1] = *reinterpret_cast<const int4v*>(lds + cur + bRd + n * 2048 + se1);
        }
        if (more) {
            gload_lds16(lds + nxt + 32768 + 0 * 8192 + w * 1024, gBs + 0 * CH);
            gload_lds16(lds + nxt + 32768 + 2 * 8192 + w * 1024, gBs + 2 * CH);
            gload_lds16(lds + nxt + 32768 + 1 * 8192 + w * 1024, gBs + 1 * CH);
            gload_lds16(lds + nxt + 32768 + 3 * 8192 + w * 1024, gBs + 3 * CH);
        }
        __builtin_amdgcn_s_setprio(1);
#pragma unroll
        for (int mi = 0; mi < 4; ++mi)
#pragma unroll
            for (int ni = 0; ni < 4; ++ni) {
                acc[mi][ni] = __builtin_amdgcn_mfma_i32_16x16x64_i8(
                    af[mi][0], bfr[ni][0], acc[mi][ni], 0, 0, 0);
                acc[mi][ni] = __builtin_amdgcn_mfma_i32_16x16x64_i8(
                    af[mi][1], bfr[ni][1], acc[mi][ni], 0, 0, 0);
            }
        __builtin_amdgcn_s_setprio(0);

        // ---------- phase 1: mi 4-7, ks0+ks1 ----------
        if (more) asm volatile("s_waitcnt vmcnt(4)" ::: "memory");
        else      asm volatile("s_waitcnt vmcnt(0)" ::: "memory");
        BAR;
#pragma unroll
        for (int j = 0; j < 4; ++j) {
            af[j][0] = *reinterpret_cast<const int4v*>(lds + cur + aRd + (4 + j) * 2048 + se0);
            af[j][1] = *reinterpret_cast<const int4v*>(lds + cur + aRd + (4 + j) * 2048 + se1);
        }
        if (more) {
            gload_lds16(lds + nxt + 0 * 8192 + w * 1024, gAs + 0 * CH);
            gload_lds16(lds + nxt + 2 * 8192 + w * 1024, gAs + 2 * CH);
            gload_lds16(lds + nxt + 1 * 8192 + w * 1024, gAs + 1 * CH);
            gload_lds16(lds + nxt + 3 * 8192 + w * 1024, gAs + 3 * CH);
        }
        __builtin_amdgcn_s_setprio(1);
#pragma unroll
        for (int mi = 0; mi < 4; ++mi)
#pragma unroll
            for (int ni = 0; ni < 4; ++ni) {
                acc[4 + mi][ni] = __builtin_amdgcn_mfma_i32_16x16x64_i8(
                    af[mi][0], bfr[ni][0], acc[4 + mi][ni], 0, 0, 0);
                acc[4 + mi][ni] = __builtin_amdgcn_mfma_i32_16x16x64_i8(
                    af[mi][1], bfr[ni][1], acc[4 + mi][ni], 0, 0, 0);
            }
        __builtin_amdgcn_s_setprio(0);
    }

    // ---- epilogue: C/D col = lane&15, row = 4*(lane>>4) + reg; dequant ----
    const int orow0 = bm * 256 + wr * 128 + fg * 4;
    const int ocol0 = bn * 256 + wc * 64 + fr;
#pragma unroll
    for (int mi = 0; mi < 8; ++mi)
#pragma unroll
        for (int r = 0; r < 4; ++r) {
            const int row = orow0 + mi * 16 + r;
            const float s = Sc[row];
            float* op = O + (size_t)row * NDIM + ocol0;
#pragma unroll
            for (int ni = 0; ni < 4; ++ni)
                op[ni * 16] = s * (float)acc[mi][ni][r];
        }
}

// ---------------- fallback: round-1 fused bf16 kernel ----------------
__global__ __launch_bounds__(256, 2) void binlin_fused(
        const float* __restrict__ X, const float* __restrict__ W,
        float* __restrict__ O) {
    const int tid = threadIdx.x;
    const int lane = tid & 63;
    const int wave = tid >> 6;
    const int wr = wave >> 1, wc = wave & 1;
    const int NWG = (MDIM / 128) * (NDIM / 128);
    int id = blockIdx.x;
    int swz = (id & 7) * (NWG >> 3) + (id >> 3);
    const int bm = swz >> 4, bn = swz & 15;

    __shared__ __align__(16) unsigned short As[128][40];
    __shared__ __align__(16) unsigned short Bs[128][40];

    const int rA = tid >> 3, kA = (tid & 7) * 4;
    const float* aPtr = X + (size_t)(bm * 128 + rA) * KDIM + kA;
    const int nB = (tid & 31) * 4, kB = (tid >> 5) * 4;
    const float* bPtr = W + (size_t)kB * NDIM + (size_t)bn * 128 + nB;

    float4v aReg[4], bReg[4];
#pragma unroll
    for (int p = 0; p < 4; ++p)
        aReg[p] = *reinterpret_cast<const float4v*>(aPtr + (size_t)(32 * p) * KDIM);
#pragma unroll
    for (int dk = 0; dk < 4; ++dk)
        bReg[dk] = *reinterpret_cast<const float4v*>(bPtr + (size_t)dk * NDIM);

    f32x4 acc[4][4];
#pragma unroll
    for (int i = 0; i < 4; ++i)
#pragma unroll
        for (int j = 0; j < 4; ++j) {
            acc[i][j][0] = 0.f; acc[i][j][1] = 0.f; acc[i][j][2] = 0.f; acc[i][j][3] = 0.f;
        }

    const int r16 = lane & 15, g8 = (lane >> 4) * 8;
    for (int kt = 0; kt < KDIM; kt += 32) {
#pragma unroll
        for (int p = 0; p < 4; ++p) {
            ushort4v v;
            v[0] = f2bf(aReg[p][0]); v[1] = f2bf(aReg[p][1]);
            v[2] = f2bf(aReg[p][2]); v[3] = f2bf(aReg[p][3]);
            *reinterpret_cast<ushort4v*>(&As[rA + 32 * p][kA]) = v;
        }
        unsigned short bb[4][4];
#pragma unroll
        for (int dk = 0; dk < 4; ++dk)
#pragma unroll
            for (int dn = 0; dn < 4; ++dn)
                bb[dn][dk] = (bReg[dk][dn] > 0.0f) ? (unsigned short)0x3F80u
                                                   : (unsigned short)0u;
#pragma unroll
        for (int dn = 0; dn < 4; ++dn) {
            ushort4v v;
            v[0] = bb[dn][0]; v[1] = bb[dn][1]; v[2] = bb[dn][2]; v[3] = bb[dn][3];
            *reinterpret_cast<ushort4v*>(&Bs[nB + dn][kB]) = v;
        }
        __syncthreads();
        if (kt + 32 < KDIM) {
#pragma unroll
            for (int p = 0; p < 4; ++p)
                aReg[p] = *reinterpret_cast<const float4v*>(
                    aPtr + (size_t)(32 * p) * KDIM + (kt + 32));
#pragma unroll
            for (int dk = 0; dk < 4; ++dk)
                bReg[dk] = *reinterpret_cast<const float4v*>(
                    bPtr + (size_t)(kt + 32 + dk) * NDIM);
        }
        short8 af[4], bf[4];
#pragma unroll
        for (int mi = 0; mi < 4; ++mi)
            af[mi] = *reinterpret_cast<const short8*>(&As[wr * 64 + mi * 16 + r16][g8]);
#pragma unroll
        for (int ni = 0; ni < 4; ++ni)
            bf[ni] = *reinterpret_cast<const short8*>(&Bs[wc * 64 + ni * 16 + r16][g8]);
#pragma unroll
        for (int mi = 0; mi < 4; ++mi)
#pragma unroll
            for (int ni = 0; ni < 4; ++ni)
                acc[mi][ni] = __builtin_amdgcn_mfma_f32_16x16x32_bf16(
                    af[mi], bf[ni], acc[mi][ni], 0, 0, 0);
        __syncthreads();
    }

    const int orow0 = bm * 128 + wr * 64 + (lane >> 4) * 4;
    const int ocol0 = bn * 128 + wc * 64 + r16;
#pragma unroll
    for (int mi = 0; mi < 4; ++mi)
#pragma unroll
        for (int ni = 0; ni < 4; ++ni)
#pragma unroll
            for (int r = 0; r < 4; ++r)
                O[(size_t)(orow0 + mi * 16 + r) * NDIM + ocol0 + ni * 16] =
                    acc[mi][ni][r];
}

extern "C" void kernel_launch(void* const* d_in, const int* in_sizes, int n_in,
                              void* d_out, int out_size, void* d_ws, size_t ws_size,
                              hipStream_t stream) {
    const float* X = (const float*)d_in[0];
    const float* W = (const float*)d_in[1];
    float* O = (float*)d_out;
    (void)in_sizes; (void)n_in; (void)out_size;

    const size_t xq_bytes = (size_t)MDIM * KDIM;          // 16 MB
    const size_t wt_bytes = (size_t)NDIM * KDIM;          // 4 MB
    const size_t sc_bytes = (size_t)MDIM * sizeof(float); // 32 KB
    const size_t need = xq_bytes + wt_bytes + sc_bytes;

    if (ws_size >= need) {
        signed char* Xq = (signed char*)d_ws;
        signed char* Wt = Xq + xq_bytes;
        float* Sc = (float*)(Wt + wt_bytes);
        hipFuncSetAttribute((const void*)gemm_i8,
                            hipFuncAttributeMaxDynamicSharedMemorySize, 131072);
        prep<<<dim3(MDIM + (KDIM / 64) * (NDIM / 64)), dim3(256), 0, stream>>>(X, W, Xq, Wt, Sc);
        gemm_i8<<<dim3((MDIM / 256) * (NDIM / 256)), dim3(512), 131072, stream>>>(Xq, Wt, Sc, O);
    } else {
        binlin_fused<<<dim3((MDIM / 128) * (NDIM / 128)), dim3(256), 0, stream>>>(X, W, O);
    }
}